// Round 12
// baseline (1075.398 us; speedup 1.0000x reference)
//
#include <hip/hip_runtime.h>

#define Bv 1024
#define Ev 64
#define NOv 512
#define L2E  1.44269504088896340736f
#define L2E2 2.88539008177792681472f

typedef _Float16 h8 __attribute__((ext_vector_type(8)));
typedef float f32x4 __attribute__((ext_vector_type(4)));
typedef int i32x8 __attribute__((ext_vector_type(8)));

#define LDH8 272   // fp8 h/rh LDS row stride (bytes); 2 rows only (batch rows)
#define LDA1 264   // a1 fp16 LDS row stride (halves); 2 rows only
#define LDX  48    // x fp16 LDS row stride (halves); 2 rows only

#define MF16(a,b,c) __builtin_amdgcn_mfma_f32_16x16x32_f16((a),(b),(c),0,0,0)
#define MFS(a,b,c) __builtin_amdgcn_mfma_scale_f32_16x16x128_f8f6f4((a),(b),(c),0,0,0,0x7F7F7F7F,0,0x7F7F7F7F)

__device__ __forceinline__ float rcpf(float x) {
    float r; asm("v_rcp_f32 %0, %1" : "=v"(r) : "v"(x)); return r;
}
__device__ __forceinline__ float ex2(float x) {
    float r; asm("v_exp_f32 %0, %1" : "=v"(r) : "v"(x)); return r;
}
__device__ __forceinline__ float sig2(float y) { return rcpf(1.0f + ex2(-y)); }
__device__ __forceinline__ float tanh2(float y) { return fmaf(2.0f, sig2(y), -1.0f); }
__device__ __forceinline__ int pk4_fp8(float a, float b, float c, float d) {
    int p = __builtin_amdgcn_cvt_pk_fp8_f32(a, b, 0, false);
    p = __builtin_amdgcn_cvt_pk_fp8_f32(c, d, p, true);
    return p;
}
__device__ __forceinline__ char fp8b(float v) {
    return (char)(__builtin_amdgcn_cvt_pk_fp8_f32(v, v, 0, false) & 0xff);
}
// owner-layout -> redistributed "gather" is the IDENTITY LANE with a component
// select (C rows are replicas with period ROWS=2): value lane L needs -- (row
// L&1, col L>>2) -- is A[(L>>2)&3] of lane L ITSELF (A's C-row l16 holds batch
// row l16&1; col 4*(L>>4)+((L>>2)&3) == L>>2). Two v_cndmask, zero cross-lane.
#define GATHER(dst, A) { \
    float lo_ = sA ? A[1] : A[0]; \
    float hi_ = sA ? A[3] : A[2]; \
    dst = sB ? hi_ : lo_; }

// ---- fused prep: 7x pack_frag8w (8 blocks each) + 3x pack_frag16(16-tile)
// + 1x pack_frag16(W2) + inv_init, dispatched by blockIdx range.
__device__ __forceinline__ void pack8_body(const float* __restrict__ src,
                                           int4* __restrict__ dst,
                                           int idx, float scale) {
    int lane = idx & 63;
    int kh = (idx >> 6) & 1;
    int ct = idx >> 7;
    int k0 = kh * 128 + (lane >> 4) * 32;
    int n = ct * 16 + (lane & 15);
    int w[8];
    #pragma unroll
    for (int q = 0; q < 8; ++q) {
        float s[4];
        #pragma unroll
        for (int j = 0; j < 4; ++j)
            s[j] = scale * src[(k0 + q * 4 + j) * 256 + n];
        w[q] = pk4_fp8(s[0], s[1], s[2], s[3]);
    }
    dst[idx * 2]     = make_int4(w[0], w[1], w[2], w[3]);
    dst[idx * 2 + 1] = make_int4(w[4], w[5], w[6], w[7]);
}
__device__ __forceinline__ void pack16_body(const float* __restrict__ src,
                                            _Float16* __restrict__ dst,
                                            int idx, int KS, int ncols, float scale) {
    int lane = idx & 63;
    int ks = (idx >> 6) % KS;
    int ct = (idx >> 6) / KS;
    int k0 = ks * 32 + (lane >> 4) * 8;
    int n = ct * 16 + (lane & 15);
    h8 v;
    #pragma unroll
    for (int j = 0; j < 8; ++j)
        v[j] = (n < ncols) ? (_Float16)(scale * src[(k0 + j) * ncols + n]) : (_Float16)0.f;
    ((h8*)dst)[idx] = v;
}

__global__ void prep_all(
    const float* __restrict__ Wr,  const float* __restrict__ Wz,  const float* __restrict__ Wh,
    const float* __restrict__ Uhr, const float* __restrict__ Uhz, const float* __restrict__ Uhn,
    const float* __restrict__ W1,
    const float* __restrict__ Wxr, const float* __restrict__ Wxz, const float* __restrict__ Wxn,
    const float* __restrict__ W2,
    int4* __restrict__ WrQ,  int4* __restrict__ WzQ,  int4* __restrict__ WhQ,
    int4* __restrict__ UhrQ, int4* __restrict__ UhzQ, int4* __restrict__ UhnQ,
    int4* __restrict__ W1Q,
    _Float16* __restrict__ WxrH, _Float16* __restrict__ WxzH, _Float16* __restrict__ WxnH,
    _Float16* __restrict__ W2H,
    int* __restrict__ inv)
{
    int b = blockIdx.x, tid = threadIdx.x;
    if (b < 56) {              // 7 mats x 8 blocks: fp8 fragment packing
        int g = b >> 3;
        int idx = (b & 7) * 256 + tid;   // 0..2047
        const float* src; int4* dst; float sc;
        switch (g) {
            case 0: src = Wr;  dst = WrQ;  sc = L2E;  break;
            case 1: src = Wz;  dst = WzQ;  sc = L2E;  break;
            case 2: src = Wh;  dst = WhQ;  sc = L2E2; break;
            case 3: src = Uhr; dst = UhrQ; sc = L2E;  break;
            case 4: src = Uhz; dst = UhzQ; sc = L2E;  break;
            case 5: src = Uhn; dst = UhnQ; sc = L2E2; break;
            default: src = W1; dst = W1Q;  sc = 1.0f; break;
        }
        pack8_body(src, dst, idx, sc);
    } else if (b < 68) {       // 3 mats x 4 blocks: fp16 packing (KS=1, 16 tiles)
        int g = (b - 56) >> 2;
        int idx = ((b - 56) & 3) * 256 + tid;   // 0..1023
        const float* src; _Float16* dst; float sc;
        switch (g) {
            case 0: src = Wxr; dst = WxrH; sc = L2E;  break;
            case 1: src = Wxz; dst = WxzH; sc = L2E;  break;
            default: src = Wxn; dst = WxnH; sc = L2E2; break;
        }
        pack16_body(src, dst, idx, 1, 256, sc);
    } else if (b < 70) {       // W2: KS=8, 1 tile, ncols=15 (512 idx)
        int idx = (b - 68) * 256 + tid;
        if (idx < 512) pack16_body(W2, W2H, idx, 8, 15, 1.0f);
    } else {                   // inv_init: 256 blocks
        int i = (b - 70) * 256 + tid;
        if (i < Ev * Bv) inv[i] = -1;
    }
}

// ---- fused gather: inv_scatter + gather_x + gather_t
__global__ void gather_all(const float* __restrict__ X, const float* __restrict__ M,
                           const int* __restrict__ bidx,
                           int* __restrict__ inv, _Float16* __restrict__ Xg,
                           float* __restrict__ Tx, float* __restrict__ Tm)
{
    int b = blockIdx.x, tid = threadIdx.x;
    if (b < 128) {             // inv_scatter
        int i = b * 256 + tid;
        if (i < Ev * NOv) {
            int e = i >> 9;
            int o = i & (NOv - 1);
            inv[e * Bv + bidx[i]] = o;
        }
    } else if (b < 4224) {     // gather_x
        int i = (b - 128) * 256 + tid;
        if (i < Ev * NOv * 32) {
            int q = i & 31, o = (i >> 5) & (NOv - 1), e = i >> 14;
            int bb = bidx[e * NOv + o];
            Xg[(e * Bv + bb) * 32 + q] = (_Float16)X[i];
        }
    } else {                   // gather_t
        int i = (b - 4224) * 256 + tid;
        if (i < Ev * NOv * 16) {
            int m = i & 15, o = (i >> 4) & (NOv - 1), e = i >> 13;
            int bb = bidx[e * NOv + o];
            int d = (e * Bv + bb) * 16 + m;
            if (m < 15) {
                Tx[d] = X[((e * NOv + o) * 16 + 1 + m) * 2];
                Tm[d] = M[(e * NOv + o) * 16 + 1 + m];
            } else {
                Tx[d] = 1.f;
                Tm[d] = 0.f;
            }
        }
    }
}

// 512 blocks x 1024 threads, 2 blocks/CU. Block owns batch rows [2b,2b+2).
// The lockstep-breaking round: occupancy was LDS-limited (150KB block = 1
// block/CU); VGPR=64 allows 32 waves/CU. LDS diet to ~17KB (drop the Uhr/Uhz
// 128KB caches; pass2/3 stream from L2 with sched_barrier fences pinning the
// loads INSIDE their passes -- round-9's spill was these loads hoisted early)
// -> 2 co-resident blocks with INDEPENDENT barriers: when block A drains at
// s_barrier, block B's waves feed the MFMA/VALU pipes. Cost: C-row replicas
// double per-CU instruction issue (2 valid rows/16-row MFMA) -- affordable at
// 25.8% MfmaUtil / 37.5% VALUBusy. All replica math generalizes: rrow=l16&1,
// redistributed row lane&1, identity-GATHER unchanged, duplicate-lane LDS
// writes are same-address-same-value (2-way conflict = free).
__global__ __launch_bounds__(1024) void gruode_main(
    const _Float16* __restrict__ Xg, const float* __restrict__ Tx, const float* __restrict__ Tm,
    const float* __restrict__ dtp,
    const float* __restrict__ br, const float* __restrict__ bz, const float* __restrict__ bh,
    const float* __restrict__ bxr, const float* __restrict__ bxz, const float* __restrict__ bxn,
    const float* __restrict__ bhr, const float* __restrict__ bhz, const float* __restrict__ bhn,
    const float* __restrict__ b1, const float* __restrict__ b2,
    const i32x8* __restrict__ WrQ, const i32x8* __restrict__ WzQ, const i32x8* __restrict__ WhQ,
    const i32x8* __restrict__ UhrQ, const i32x8* __restrict__ UhzQ, const i32x8* __restrict__ UhnQ,
    const i32x8* __restrict__ W1Q,
    const h8* __restrict__ WxrH, const h8* __restrict__ WxzH, const h8* __restrict__ WxnH,
    const h8* __restrict__ W2H,
    const int* __restrict__ inv, double* __restrict__ partials)
{
    __shared__ __align__(16) h8       W2L[512];                 // 8KB
    __shared__ __align__(16) char     hb2[2][2 * LDH8];
    __shared__ __align__(16) _Float16 a1s[2 * LDA1];
    __shared__ __align__(16) _Float16 x16d[2][2 * LDX];
    __shared__ __align__(16) float    bias_s[5][256];
    __shared__ __align__(16) float    b2s[16];
    __shared__ int    obsi2[2][16];
    __shared__ double wred[16][4];

    const int tid  = threadIdx.x;
    const int lane = tid & 63;
    const int wid  = tid >> 6;
    const int l16  = lane & 15;    // owner layout: C row (batch row replica index)
    const int lg   = lane >> 4;
    const int n0   = wid * 16 + lg * 4;
    const int row0 = blockIdx.x * 2;
    const float dtv = dtp[0];
    const int rrow = l16 & 1;      // valid batch row for B-operand reads (broadcast)

    // redistributed layout: lane L owns (row rho2 = L&1, col gam); lanes L and
    // L^2 are duplicates (same row/col) -- all math replicates bit-identically.
    const int rho2 = lane & 1;
    const int kap = lane >> 2;
    const int gam = wid * 16 + kap;
    const int hoff = rho2 * LDH8 + gam;
    const bool sA = (kap & 1) != 0;
    const bool sB = (kap & 2) != 0;
    const int sbase = 64 * lg + 4 * rrow;

    if (tid < 256) {
        bias_s[0][tid] = (bxr[tid] + bhr[tid]) * L2E;
        bias_s[1][tid] = (bxz[tid] + bhz[tid]) * L2E;
        bias_s[2][tid] = bxn[tid] * L2E2;
    } else if (tid < 512) {
        int t = tid - 256;
        bias_s[3][t] = bhn[t] * L2E2;
        bias_s[4][t] = b1[t];
    }
    if (tid < 16) b2s[tid] = (tid < 15) ? b2[tid] : 0.f;
    if (tid < 136) {   // 2*LDH8 bytes = 136 ints per buffer
        ((int*)hb2[0])[tid] = 0;
        ((int*)hb2[1])[tid] = 0;
    }
    if (tid < 512) W2L[tid] = W2H[tid];
    // event-0 input prefetch (later events prefetched during extras)
    if (tid < 16) obsi2[0][tid] = (tid < 2) ? inv[row0 + tid] : -1;
    if (tid < 64) {
        int row = tid >> 5, q = tid & 31;
        x16d[0][row * LDX + q] = Xg[(row0 + row) * 32 + q];
    }

    // euler biases as per-lane scalars (redistributed layout: one col/lane)
    const float bRs = br[gam] * L2E;
    const float bZs = bz[gam] * L2E;
    const float bUs = bh[gam] * L2E2;

    // pin euler weight^T fp8 slices: 3 mats x 2 K-halves x i32x8 = 48 regs
    i32x8 wr0 = WrQ[(wid * 2 + 0) * 64 + lane], wr1 = WrQ[(wid * 2 + 1) * 64 + lane];
    i32x8 wz0 = WzQ[(wid * 2 + 0) * 64 + lane], wz1 = WzQ[(wid * 2 + 1) * 64 + lane];
    i32x8 wh0 = WhQ[(wid * 2 + 0) * 64 + lane], wh1 = WhQ[(wid * 2 + 1) * 64 + lane];

    float hs = 0.f;                // fp32 h master, redistributed layout
    double am0 = 0.0, am1 = 0.0, am2 = 0.0, am3 = 0.0;
    const f32x4 zf = {0.f, 0.f, 0.f, 0.f};
    __syncthreads();

    #pragma unroll 1
    for (int e = 0; e < Ev; ++e) {
        // uniform buffer selects
        char* __restrict__ HB = hb2[e & 1];
        char* __restrict__ RB = hb2[(e & 1) ^ 1];
        const _Float16* __restrict__ xs = x16d[e & 1];
        const int* __restrict__ obs = obsi2[e & 1];

        // ---------------- 4 Euler steps (pure LDS/VALU/MFMA) ----------------
        float zs = 0.f;
        for (int s = 0; s < 4; ++s) {
            f32x4 aR = zf, aZ = zf;
            {
                i32x8 hb = *(const i32x8*)&HB[rrow * LDH8 + lg * 32];
                aR = MFS(wr0, hb, aR); aZ = MFS(wz0, hb, aZ);
                hb = *(const i32x8*)&HB[rrow * LDH8 + 128 + lg * 32];
                aR = MFS(wr1, hb, aR); aZ = MFS(wz1, hb, aZ);
            }
            float rpre, zpre;
            GATHER(rpre, aR);
            GATHER(zpre, aZ);
            float rv = sig2(rpre + bRs);
            zs = sig2(zpre + bZs);
            RB[hoff] = fp8b(rv * hs);
            __syncthreads();
            // U phase: two INDEPENDENT half-K accumulators, summed post-GATHER
            f32x4 aU0 = zf, aU1 = zf;
            {
                i32x8 rb = *(const i32x8*)&RB[rrow * LDH8 + lg * 32];
                aU0 = MFS(wh0, rb, aU0);
                rb = *(const i32x8*)&RB[rrow * LDH8 + 128 + lg * 32];
                aU1 = MFS(wh1, rb, aU1);
            }
            float u0, u1;
            GATHER(u0, aU0);
            GATHER(u1, aU1);
            float u = tanh2(u0 + u1 + bUs);
            hs = hs + dtv * (1.f - zs) * (u - hs);
            HB[hoff] = fp8b(hs);
            __syncthreads();
        }
        // fence: keep the extras' global loads out of the euler region
        __builtin_amdgcn_sched_barrier(0);

        // -------- event extras (owner layout GEMMs). Writes target RB. --------
        i32x8 hb0 = *(const i32x8*)&HB[rrow * LDH8 + lg * 32];
        i32x8 hb1 = *(const i32x8*)&HB[rrow * LDH8 + 128 + lg * 32];
        // pass1: nH (Uhn) + a1 (W1) -- L2 streams, issue+consume immediately
        f32x4 aN = *(const f32x4*)&bias_s[3][n0];
        {
            f32x4 aW = *(const f32x4*)&bias_s[4][n0];
            aN = MFS(UhnQ[(wid * 2 + 0) * 64 + lane], hb0, aN);
            aW = MFS(W1Q[(wid * 2 + 0) * 64 + lane], hb0, aW);
            aN = MFS(UhnQ[(wid * 2 + 1) * 64 + lane], hb1, aN);
            aW = MFS(W1Q[(wid * 2 + 1) * 64 + lane], hb1, aW);
            if (l16 < 2) {
                _Float16 a1v[4];
                #pragma unroll
                for (int r = 0; r < 4; ++r)
                    a1v[r] = (_Float16)fmaxf(aW[r], 0.f);
                *(long*)&a1s[l16 * LDA1 + n0] = *(const long*)a1v;
            }
        }
        // prefetch NEXT event's inputs (wave 0); drains at the closing barrier
        {
            int en = (e + 1 < Ev) ? e + 1 : e;
            int nb = (e + 1) & 1;
            if (tid < 16) obsi2[nb][tid] = (tid < 2) ? inv[en * Bv + row0 + tid] : -1;
            if (tid < 64) {
                int row = tid >> 5, q = tid & 31;
                x16d[nb][row * LDX + q] = Xg[(en * Bv + row0 + row) * 32 + q];
            }
        }
        // current event's targets/masks (wave 0; consumed after the barrier)
        float4 txv = {0.f,0.f,0.f,0.f}, tmv = {0.f,0.f,0.f,0.f};
        if (wid == 0) {
            int gr = row0 + l16; if (gr > Bv - 1) gr = Bv - 1;
            txv = *(const float4*)&Tx[(e * Bv + gr) * 16 + lg * 4];
            tmv = *(const float4*)&Tm[(e * Bv + gr) * 16 + lg * 4];
        }
        // fence: pin pass2's Uhr loads inside pass2 (round-9 lesson: hoisted
        // weight streams -> 32 live VGPRs across passes -> catastrophic spill)
        __builtin_amdgcn_sched_barrier(0);
        // pass2: r gate -- Uhr streamed from L2, immediate consume
        float rg[4];
        {
            f32x4 aG = *(const f32x4*)&bias_s[0][n0];
            aG = MFS(UhrQ[(wid * 2 + 0) * 64 + lane], hb0, aG);
            aG = MFS(UhrQ[(wid * 2 + 1) * 64 + lane], hb1, aG);
            h8 bx = *(const h8*)&xs[rrow * LDX + lg * 8];
            aG = MF16(WxrH[wid * 64 + lane], bx, aG);
            #pragma unroll
            for (int r = 0; r < 4; ++r)
                rg[r] = sig2(aG[r]);
        }
        // fence: pin pass3's Uhz loads inside pass3
        __builtin_amdgcn_sched_barrier(0);
        // pass3: z gate + nX -> h-new (owner), commit new h to RB (buffer swap)
        {
            f32x4 aG = *(const f32x4*)&bias_s[1][n0];
            aG = MFS(UhzQ[(wid * 2 + 0) * 64 + lane], hb0, aG);
            aG = MFS(UhzQ[(wid * 2 + 1) * 64 + lane], hb1, aG);
            h8 bx = *(const h8*)&xs[rrow * LDX + lg * 8];
            aG = MF16(WxzH[wid * 64 + lane], bx, aG);
            f32x4 aNx = *(const f32x4*)&bias_s[2][n0];
            aNx = MF16(WxnH[wid * 64 + lane], bx, aNx);
            float how[4];
            #pragma unroll
            for (int r = 0; r < 4; ++r)
                how[r] = __int_as_float(__builtin_amdgcn_ds_bpermute(sbase + 16 * r, __float_as_int(hs)));
            float hn[4];
            #pragma unroll
            for (int r = 0; r < 4; ++r) {
                float zg = sig2(aG[r]);
                float nv = tanh2(aNx[r] + rg[r] * aN[r]);
                hn[r] = (1.f - zg) * nv + zg * how[r];
            }
            float hng;
            GATHER(hng, hn);
            if (obs[rho2] >= 0) hs = hng;
            RB[hoff] = fp8b(hs);
        }
        __syncthreads();   // a1s + RB(new h) + prefetch buffers visible
        // W2 GEMM + metrics: wave 0 only, overlaps other waves' next-event
        // phase-1 -- W2 from LDS cache (straggler path)
        if (wid == 0) {
            f32x4 aP = *(const f32x4*)&b2s[lg * 4];
            f32x4 aQ = zf;
            #pragma unroll
            for (int ks = 0; ks < 4; ++ks) {
                h8 ba = *(const h8*)&a1s[rrow * LDA1 + (2 * ks) * 32 + lg * 8];
                aP = MF16(W2L[(2 * ks) * 64 + lane], ba, aP);
                h8 bb = *(const h8*)&a1s[rrow * LDA1 + (2 * ks + 1) * 32 + lg * 8];
                aQ = MF16(W2L[(2 * ks + 1) * 64 + lane], bb, aQ);
            }
            if (obs[l16] >= 0) {
                float m0 = 0.f, m1 = 0.f, m2 = 0.f, m3 = 0.f;
                #pragma unroll
                for (int r = 0; r < 4; ++r) {
                    float p  = aP[r] + aQ[r];
                    float xt = ((const float*)&txv)[r];
                    float mt = ((const float*)&tmv)[r];
                    float diff = xt - p;
                    m0 += diff * diff * mt;
                    m1 += fabsf(diff) * mt;
                    m2 += fabsf(diff) * rcpf(xt + 1e-8f) * mt;
                    m3 += mt;
                }
                am0 += (double)m0;
                am1 += (double)m1;
                am2 += (double)m2;
                am3 += (double)m3;
            }
        }
    }

    __syncthreads();
    // deterministic metric reduction
    double v[4] = {am0, am1, am2, am3};
    #pragma unroll
    for (int m = 0; m < 4; ++m) {
        double t = v[m];
        for (int off = 32; off; off >>= 1) t += __shfl_down(t, off);
        if (lane == 0) wred[wid][m] = t;
    }
    __syncthreads();
    if (tid == 0) {
        for (int m = 0; m < 4; ++m) {
            double t = 0.0;
            for (int w = 0; w < 16; ++w) t += wred[w][m];
            partials[blockIdx.x * 4 + m] = t;
        }
    }
}

__global__ void finalize_k(const double* __restrict__ partials, float* __restrict__ out) {
    __shared__ double sd[4][4];
    int t = threadIdx.x;   // 256 threads, 512 block-partials
    int l = t & 63, w = t >> 6;
    double v0 = partials[t * 4 + 0] + partials[(t + 256) * 4 + 0];
    double v1 = partials[t * 4 + 1] + partials[(t + 256) * 4 + 1];
    double v2 = partials[t * 4 + 2] + partials[(t + 256) * 4 + 2];
    double v3 = partials[t * 4 + 3] + partials[(t + 256) * 4 + 3];
    for (int off = 32; off; off >>= 1) {
        v0 += __shfl_down(v0, off);
        v1 += __shfl_down(v1, off);
        v2 += __shfl_down(v2, off);
        v3 += __shfl_down(v3, off);
    }
    if (l == 0) { sd[w][0] = v0; sd[w][1] = v1; sd[w][2] = v2; sd[w][3] = v3; }
    __syncthreads();
    if (t == 0) {
        double r0 = 0, r1 = 0, r2 = 0, r3 = 0;
        for (int i = 0; i < 4; ++i) { r0 += sd[i][0]; r1 += sd[i][1]; r2 += sd[i][2]; r3 += sd[i][3]; }
        out[0] = (float)(r0 / r3);
        out[1] = (float)(r1 / r3);
        out[2] = (float)(r2 / r3);
    }
}

extern "C" void kernel_launch(void* const* d_in, const int* in_sizes, int n_in,
                              void* d_out, int out_size, void* d_ws, size_t ws_size,
                              hipStream_t stream) {
    const float* X   = (const float*)d_in[0];
    const float* M   = (const float*)d_in[1];
    const int*  bidx = (const int*)d_in[2];
    const float* dtp = (const float*)d_in[3];
    const float* Wr  = (const float*)d_in[4];
    const float* brr = (const float*)d_in[5];
    const float* Wz  = (const float*)d_in[6];
    const float* bzz = (const float*)d_in[7];
    const float* Wh  = (const float*)d_in[8];
    const float* bhh = (const float*)d_in[9];
    const float* Wxr = (const float*)d_in[10];
    const float* Wxz = (const float*)d_in[11];
    const float* Wxn = (const float*)d_in[12];
    const float* Uhr = (const float*)d_in[13];
    const float* Uhz = (const float*)d_in[14];
    const float* Uhn = (const float*)d_in[15];
    const float* bxr = (const float*)d_in[16];
    const float* bxz = (const float*)d_in[17];
    const float* bxn = (const float*)d_in[18];
    const float* bhr = (const float*)d_in[19];
    const float* bhz = (const float*)d_in[20];
    const float* bhn = (const float*)d_in[21];
    const float* W1  = (const float*)d_in[22];
    const float* b1  = (const float*)d_in[23];
    const float* W2  = (const float*)d_in[24];
    const float* b2  = (const float*)d_in[25];

    char* w = (char*)d_ws;
    i32x8* WrQ  = (i32x8*)(w + 0 * 65536);
    i32x8* WzQ  = (i32x8*)(w + 1 * 65536);
    i32x8* WhQ  = (i32x8*)(w + 2 * 65536);
    i32x8* UhrQ = (i32x8*)(w + 3 * 65536);
    i32x8* UhzQ = (i32x8*)(w + 4 * 65536);
    i32x8* UhnQ = (i32x8*)(w + 5 * 65536);
    i32x8* W1Q  = (i32x8*)(w + 6 * 65536);
    _Float16* WxrH = (_Float16*)(w + 458752);
    _Float16* WxzH = (_Float16*)(w + 475136);
    _Float16* WxnH = (_Float16*)(w + 491520);
    _Float16* W2H  = (_Float16*)(w + 507904);
    int* inv = (int*)(w + 516096);
    _Float16* Xg = (_Float16*)(w + 778240);
    float* Tx = (float*)(w + 4972544);
    float* Tm = (float*)(w + 9166848);
    double* partials = (double*)(w + 13361152);   // 512*4 doubles = 16KB

    prep_all<<<326, 256, 0, stream>>>(
        Wr, Wz, Wh, Uhr, Uhz, Uhn, W1, Wxr, Wxz, Wxn, W2,
        (int4*)WrQ, (int4*)WzQ, (int4*)WhQ, (int4*)UhrQ, (int4*)UhzQ,
        (int4*)UhnQ, (int4*)W1Q, WxrH, WxzH, WxnH, W2H, inv);
    gather_all<<<6272, 256, 0, stream>>>(X, M, bidx, inv, Xg, Tx, Tm);

    gruode_main<<<512, 1024, 0, stream>>>(Xg, Tx, Tm, dtp,
        brr, bzz, bhh, bxr, bxz, bxn, bhr, bhz, bhn, b1, b2,
        WrQ, WzQ, WhQ, UhrQ, UhzQ, UhnQ, W1Q,
        (const h8*)WxrH, (const h8*)WxzH, (const h8*)WxnH, (const h8*)W2H,
        inv, partials);

    finalize_k<<<1, 256, 0, stream>>>(partials, (float*)d_out);
}

// Round 13
// 441.572 us; speedup vs baseline: 2.4354x; 2.4354x over previous
//
#include <hip/hip_runtime.h>

#define Bv 1024
#define Ev 64
#define NOv 512
#define L2E  1.44269504088896340736f
#define L2E2 2.88539008177792681472f

typedef _Float16 h8 __attribute__((ext_vector_type(8)));
typedef float f32x4 __attribute__((ext_vector_type(4)));
typedef int i32x8 __attribute__((ext_vector_type(8)));

#define LDH8 272   // fp8 h/rh LDS row stride (bytes); 4 rows only (batch rows)
#define LDA1 264   // a1 fp16 LDS row stride (halves); 4 rows only
#define LDX  48    // x fp16 LDS row stride (halves); 4 rows only

#define MF16(a,b,c) __builtin_amdgcn_mfma_f32_16x16x32_f16((a),(b),(c),0,0,0)
#define MFS(a,b,c) __builtin_amdgcn_mfma_scale_f32_16x16x128_f8f6f4((a),(b),(c),0,0,0,0x7F7F7F7F,0,0x7F7F7F7F)

__device__ __forceinline__ float rcpf(float x) {
    float r; asm("v_rcp_f32 %0, %1" : "=v"(r) : "v"(x)); return r;
}
__device__ __forceinline__ float ex2(float x) {
    float r; asm("v_exp_f32 %0, %1" : "=v"(r) : "v"(x)); return r;
}
__device__ __forceinline__ float sig2(float y) { return rcpf(1.0f + ex2(-y)); }
__device__ __forceinline__ float tanh2(float y) { return fmaf(2.0f, sig2(y), -1.0f); }
__device__ __forceinline__ int pk4_fp8(float a, float b, float c, float d) {
    int p = __builtin_amdgcn_cvt_pk_fp8_f32(a, b, 0, false);
    p = __builtin_amdgcn_cvt_pk_fp8_f32(c, d, p, true);
    return p;
}
__device__ __forceinline__ char fp8b(float v) {
    return (char)(__builtin_amdgcn_cvt_pk_fp8_f32(v, v, 0, false) & 0xff);
}
// owner-layout -> redistributed "gather" is the IDENTITY LANE with a component
// select (C rows 4..15 are replicas of 0..3): value lane L needs is A[(L>>2)&3]
// of lane L ITSELF. Two v_cndmask ops, zero cross-lane ops.
#define GATHER(dst, A) { \
    float lo_ = sA ? A[1] : A[0]; \
    float hi_ = sA ? A[3] : A[2]; \
    dst = sB ? hi_ : lo_; }

// assemble i32x8 MFS operand from de-interleaved LDS halves (lane-stride 16B
// per read -> bank-conflict-free ds_read_b128)
__device__ __forceinline__ i32x8 ld8(const int4* __restrict__ A,
                                     const int4* __restrict__ B, int idx) {
    int4 lo = A[idx], hi = B[idx];
    i32x8 w;
    w[0] = lo.x; w[1] = lo.y; w[2] = lo.z; w[3] = lo.w;
    w[4] = hi.x; w[5] = hi.y; w[6] = hi.z; w[7] = hi.w;
    return w;
}

// ---- fused prep: 7x pack_frag8w (8 blocks each) + 3x pack_frag16(16-tile)
// + 1x pack_frag16(W2) + inv_init, dispatched by blockIdx range.
__device__ __forceinline__ void pack8_body(const float* __restrict__ src,
                                           int4* __restrict__ dst,
                                           int idx, float scale) {
    int lane = idx & 63;
    int kh = (idx >> 6) & 1;
    int ct = idx >> 7;
    int k0 = kh * 128 + (lane >> 4) * 32;
    int n = ct * 16 + (lane & 15);
    int w[8];
    #pragma unroll
    for (int q = 0; q < 8; ++q) {
        float s[4];
        #pragma unroll
        for (int j = 0; j < 4; ++j)
            s[j] = scale * src[(k0 + q * 4 + j) * 256 + n];
        w[q] = pk4_fp8(s[0], s[1], s[2], s[3]);
    }
    dst[idx * 2]     = make_int4(w[0], w[1], w[2], w[3]);
    dst[idx * 2 + 1] = make_int4(w[4], w[5], w[6], w[7]);
}
__device__ __forceinline__ void pack16_body(const float* __restrict__ src,
                                            _Float16* __restrict__ dst,
                                            int idx, int KS, int ncols, float scale) {
    int lane = idx & 63;
    int ks = (idx >> 6) % KS;
    int ct = (idx >> 6) / KS;
    int k0 = ks * 32 + (lane >> 4) * 8;
    int n = ct * 16 + (lane & 15);
    h8 v;
    #pragma unroll
    for (int j = 0; j < 8; ++j)
        v[j] = (n < ncols) ? (_Float16)(scale * src[(k0 + j) * ncols + n]) : (_Float16)0.f;
    ((h8*)dst)[idx] = v;
}

__global__ void prep_all(
    const float* __restrict__ Wr,  const float* __restrict__ Wz,  const float* __restrict__ Wh,
    const float* __restrict__ Uhr, const float* __restrict__ Uhz, const float* __restrict__ Uhn,
    const float* __restrict__ W1,
    const float* __restrict__ Wxr, const float* __restrict__ Wxz, const float* __restrict__ Wxn,
    const float* __restrict__ W2,
    int4* __restrict__ WrQ,  int4* __restrict__ WzQ,  int4* __restrict__ WhQ,
    int4* __restrict__ UhrQ, int4* __restrict__ UhzQ, int4* __restrict__ UhnQ,
    int4* __restrict__ W1Q,
    _Float16* __restrict__ WxrH, _Float16* __restrict__ WxzH, _Float16* __restrict__ WxnH,
    _Float16* __restrict__ W2H,
    int* __restrict__ inv)
{
    int b = blockIdx.x, tid = threadIdx.x;
    if (b < 56) {              // 7 mats x 8 blocks: fp8 fragment packing
        int g = b >> 3;
        int idx = (b & 7) * 256 + tid;   // 0..2047
        const float* src; int4* dst; float sc;
        switch (g) {
            case 0: src = Wr;  dst = WrQ;  sc = L2E;  break;
            case 1: src = Wz;  dst = WzQ;  sc = L2E;  break;
            case 2: src = Wh;  dst = WhQ;  sc = L2E2; break;
            case 3: src = Uhr; dst = UhrQ; sc = L2E;  break;
            case 4: src = Uhz; dst = UhzQ; sc = L2E;  break;
            case 5: src = Uhn; dst = UhnQ; sc = L2E2; break;
            default: src = W1; dst = W1Q;  sc = 1.0f; break;
        }
        pack8_body(src, dst, idx, sc);
    } else if (b < 68) {       // 3 mats x 4 blocks: fp16 packing (KS=1, 16 tiles)
        int g = (b - 56) >> 2;
        int idx = ((b - 56) & 3) * 256 + tid;   // 0..1023
        const float* src; _Float16* dst; float sc;
        switch (g) {
            case 0: src = Wxr; dst = WxrH; sc = L2E;  break;
            case 1: src = Wxz; dst = WxzH; sc = L2E;  break;
            default: src = Wxn; dst = WxnH; sc = L2E2; break;
        }
        pack16_body(src, dst, idx, 1, 256, sc);
    } else if (b < 70) {       // W2: KS=8, 1 tile, ncols=15 (512 idx)
        int idx = (b - 68) * 256 + tid;
        if (idx < 512) pack16_body(W2, W2H, idx, 8, 15, 1.0f);
    } else {                   // inv_init: 256 blocks
        int i = (b - 70) * 256 + tid;
        if (i < Ev * Bv) inv[i] = -1;
    }
}

// ---- fused gather: inv_scatter + gather_x + gather_t (mutually independent;
// inv_init completed in prep_all, stream-ordered). Replaces 3 launches.
__global__ void gather_all(const float* __restrict__ X, const float* __restrict__ M,
                           const int* __restrict__ bidx,
                           int* __restrict__ inv, _Float16* __restrict__ Xg,
                           float* __restrict__ Tx, float* __restrict__ Tm)
{
    int b = blockIdx.x, tid = threadIdx.x;
    if (b < 128) {             // inv_scatter
        int i = b * 256 + tid;
        if (i < Ev * NOv) {
            int e = i >> 9;
            int o = i & (NOv - 1);
            inv[e * Bv + bidx[i]] = o;
        }
    } else if (b < 4224) {     // gather_x
        int i = (b - 128) * 256 + tid;
        if (i < Ev * NOv * 32) {
            int q = i & 31, o = (i >> 5) & (NOv - 1), e = i >> 14;
            int bb = bidx[e * NOv + o];
            Xg[(e * Bv + bb) * 32 + q] = (_Float16)X[i];
        }
    } else {                   // gather_t
        int i = (b - 4224) * 256 + tid;
        if (i < Ev * NOv * 16) {
            int m = i & 15, o = (i >> 4) & (NOv - 1), e = i >> 13;
            int bb = bidx[e * NOv + o];
            int d = (e * Bv + bb) * 16 + m;
            if (m < 15) {
                Tx[d] = X[((e * NOv + o) * 16 + 1 + m) * 2];
                Tm[d] = M[(e * NOv + o) * 16 + 1 + m];
            } else {
                Tx[d] = 1.f;
                Tm[d] = 0.f;
            }
        }
    }
}

// 256 blocks x 1024 threads (16 waves). Block owns batch rows [4b,4b+4).
// VERIFIED round-11 main kernel, UNCHANGED (497us dispatch / 441.9us bench):
// identity GATHER, ping-pong h buffers, Uhr/Uhz/W2 LDS cache, zero-vmem euler
// phases, sched_barrier fence, prefetch in extras, U-phase split accumulators.
// Rule bank (4x confirmed):
//  - never extend >=8-VGPR liveness across a phase boundary at the 64-arch-
//    VGPR budget; L2 streams must issue+consume within one pass.
//  - occupancy is UNIFIED-REGISTER-limited at 16 waves/CU (128 regs/wave out
//    of the 2048/SIMD pool) -- co-residency of a second block is structurally
//    impossible (round-12: LDS diet to 17KB left occupancy at 46%, paid 2x
//    issue for nothing). 16-wave lockstep is the floor for this algorithm.
__global__ __launch_bounds__(1024) void gruode_main(
    const _Float16* __restrict__ Xg, const float* __restrict__ Tx, const float* __restrict__ Tm,
    const float* __restrict__ dtp,
    const float* __restrict__ br, const float* __restrict__ bz, const float* __restrict__ bh,
    const float* __restrict__ bxr, const float* __restrict__ bxz, const float* __restrict__ bxn,
    const float* __restrict__ bhr, const float* __restrict__ bhz, const float* __restrict__ bhn,
    const float* __restrict__ b1, const float* __restrict__ b2,
    const i32x8* __restrict__ WrQ, const i32x8* __restrict__ WzQ, const i32x8* __restrict__ WhQ,
    const i32x8* __restrict__ UhrQ, const i32x8* __restrict__ UhzQ, const i32x8* __restrict__ UhnQ,
    const i32x8* __restrict__ W1Q,
    const h8* __restrict__ WxrH, const h8* __restrict__ WxzH, const h8* __restrict__ WxnH,
    const h8* __restrict__ W2H,
    const int* __restrict__ inv, double* __restrict__ partials)
{
    __shared__ __align__(16) int4     UhrA[2048], UhrB[2048];   // 64KB
    __shared__ __align__(16) int4     UhzA[2048], UhzB[2048];   // 64KB
    __shared__ __align__(16) h8       W2L[512];                 // 8KB
    __shared__ __align__(16) char     hb2[2][4 * LDH8];
    __shared__ __align__(16) _Float16 a1s[4 * LDA1];
    __shared__ __align__(16) _Float16 x16d[2][4 * LDX];
    __shared__ __align__(16) float    bias_s[5][256];
    __shared__ __align__(16) float    b2s[16];
    __shared__ int    obsi2[2][16];
    __shared__ double wred[16][4];

    const int tid  = threadIdx.x;
    const int lane = tid & 63;
    const int wid  = tid >> 6;
    const int l16  = lane & 15;    // owner layout: C row (batch row replica index)
    const int lg   = lane >> 4;
    const int n0   = wid * 16 + lg * 4;
    const int row0 = blockIdx.x * 4;
    const float dtv = dtp[0];
    const int rrow = l16 & 3;      // valid batch row for B-operand reads (broadcast)

    // redistributed layout: lane L owns (row rho = L&3, col gam = wid*16 + (L>>2))
    const int rho = lane & 3;
    const int kap = lane >> 2;
    const int gam = wid * 16 + kap;
    const int hoff = rho * LDH8 + gam;
    const bool sA = (kap & 1) != 0;
    const bool sB = (kap & 2) != 0;
    const int sbase = 64 * lg + 4 * rrow;

    if (tid < 256) {
        bias_s[0][tid] = (bxr[tid] + bhr[tid]) * L2E;
        bias_s[1][tid] = (bxz[tid] + bhz[tid]) * L2E;
        bias_s[2][tid] = bxn[tid] * L2E2;
    } else if (tid < 512) {
        int t = tid - 256;
        bias_s[3][t] = bhn[t] * L2E2;
        bias_s[4][t] = b1[t];
    }
    if (tid < 16) b2s[tid] = (tid < 15) ? b2[tid] : 0.f;
    if (tid < LDH8) {   // 4*LDH8 bytes = LDH8 ints each
        ((int*)hb2[0])[tid] = 0;
        ((int*)hb2[1])[tid] = 0;
    }
    // one-time LDS weight cache fill (de-interleaved 16B halves)
    for (int i = tid; i < 2048; i += 1024) {
        const int4* s1 = (const int4*)&UhrQ[i];
        UhrA[i] = s1[0]; UhrB[i] = s1[1];
        const int4* s2 = (const int4*)&UhzQ[i];
        UhzA[i] = s2[0]; UhzB[i] = s2[1];
    }
    if (tid < 512) W2L[tid] = W2H[tid];
    // event-0 input prefetch (later events prefetched during extras)
    if (tid < 16) obsi2[0][tid] = (tid < 4) ? inv[row0 + tid] : -1;
    if (tid < 128) {
        int row = tid >> 5, q = tid & 31;
        x16d[0][row * LDX + q] = Xg[(row0 + row) * 32 + q];
    }

    // euler biases as per-lane scalars (redistributed layout: one col/lane)
    const float bRs = br[gam] * L2E;
    const float bZs = bz[gam] * L2E;
    const float bUs = bh[gam] * L2E2;

    // pin euler weight^T fp8 slices: 3 mats x 2 K-halves x i32x8 = 48 regs
    i32x8 wr0 = WrQ[(wid * 2 + 0) * 64 + lane], wr1 = WrQ[(wid * 2 + 1) * 64 + lane];
    i32x8 wz0 = WzQ[(wid * 2 + 0) * 64 + lane], wz1 = WzQ[(wid * 2 + 1) * 64 + lane];
    i32x8 wh0 = WhQ[(wid * 2 + 0) * 64 + lane], wh1 = WhQ[(wid * 2 + 1) * 64 + lane];

    float hs = 0.f;                // fp32 h master, redistributed layout
    double am0 = 0.0, am1 = 0.0, am2 = 0.0, am3 = 0.0;
    const f32x4 zf = {0.f, 0.f, 0.f, 0.f};
    __syncthreads();

    #pragma unroll 1
    for (int e = 0; e < Ev; ++e) {
        // uniform buffer selects
        char* __restrict__ HB = hb2[e & 1];
        char* __restrict__ RB = hb2[(e & 1) ^ 1];
        const _Float16* __restrict__ xs = x16d[e & 1];
        const int* __restrict__ obs = obsi2[e & 1];

        // ---------------- 4 Euler steps (pure LDS/VALU/MFMA) ----------------
        float zs = 0.f;
        for (int s = 0; s < 4; ++s) {
            f32x4 aR = zf, aZ = zf;
            {
                i32x8 hb = *(const i32x8*)&HB[rrow * LDH8 + lg * 32];
                aR = MFS(wr0, hb, aR); aZ = MFS(wz0, hb, aZ);
                hb = *(const i32x8*)&HB[rrow * LDH8 + 128 + lg * 32];
                aR = MFS(wr1, hb, aR); aZ = MFS(wz1, hb, aZ);
            }
            float rpre, zpre;
            GATHER(rpre, aR);
            GATHER(zpre, aZ);
            float rv = sig2(rpre + bRs);
            zs = sig2(zpre + bZs);
            RB[hoff] = fp8b(rv * hs);
            __syncthreads();
            // U phase: two INDEPENDENT half-K accumulators, summed post-GATHER
            f32x4 aU0 = zf, aU1 = zf;
            {
                i32x8 rb = *(const i32x8*)&RB[rrow * LDH8 + lg * 32];
                aU0 = MFS(wh0, rb, aU0);
                rb = *(const i32x8*)&RB[rrow * LDH8 + 128 + lg * 32];
                aU1 = MFS(wh1, rb, aU1);
            }
            float u0, u1;
            GATHER(u0, aU0);
            GATHER(u1, aU1);
            float u = tanh2(u0 + u1 + bUs);
            hs = hs + dtv * (1.f - zs) * (u - hs);
            HB[hoff] = fp8b(hs);
            __syncthreads();
        }
        // fence: keep the extras' global loads out of the euler region
        __builtin_amdgcn_sched_barrier(0);

        // -------- event extras (owner layout GEMMs). Writes target RB (the
        // old rh scratch), so NO barrier is needed before pass3 rewrites. --------
        i32x8 hb0 = *(const i32x8*)&HB[rrow * LDH8 + lg * 32];
        i32x8 hb1 = *(const i32x8*)&HB[rrow * LDH8 + 128 + lg * 32];
        // pass1: nH (Uhn) + a1 (W1) -- weights stream from L2 (issued first,
        // consumed immediately: short liveness by design)
        f32x4 aN = *(const f32x4*)&bias_s[3][n0];
        {
            f32x4 aW = *(const f32x4*)&bias_s[4][n0];
            aN = MFS(UhnQ[(wid * 2 + 0) * 64 + lane], hb0, aN);
            aW = MFS(W1Q[(wid * 2 + 0) * 64 + lane], hb0, aW);
            aN = MFS(UhnQ[(wid * 2 + 1) * 64 + lane], hb1, aN);
            aW = MFS(W1Q[(wid * 2 + 1) * 64 + lane], hb1, aW);
            if (l16 < 4) {
                _Float16 a1v[4];
                #pragma unroll
                for (int r = 0; r < 4; ++r)
                    a1v[r] = (_Float16)fmaxf(aW[r], 0.f);
                *(long*)&a1s[l16 * LDA1 + n0] = *(const long*)a1v;
            }
        }
        // prefetch NEXT event's inputs into the alternate buffers; issued
        // ~1500cy before the extras closing barrier, so its drain is free
        {
            int en = (e + 1 < Ev) ? e + 1 : e;
            int nb = (e + 1) & 1;
            if (tid < 16) obsi2[nb][tid] = (tid < 4) ? inv[en * Bv + row0 + tid] : -1;
            if (tid < 128) {
                int row = tid >> 5, q = tid & 31;
                x16d[nb][row * LDX + q] = Xg[(en * Bv + row0 + row) * 32 + q];
            }
        }
        // current event's targets/masks (wave 0; consumed after the barrier)
        float4 txv = {0.f,0.f,0.f,0.f}, tmv = {0.f,0.f,0.f,0.f};
        if (wid == 0) {
            int gr = row0 + l16; if (gr > Bv - 1) gr = Bv - 1;
            txv = *(const float4*)&Tx[(e * Bv + gr) * 16 + lg * 4];
            tmv = *(const float4*)&Tm[(e * Bv + gr) * 16 + lg * 4];
        }
        // pass2: r gate -- Uhr from LDS cache
        float rg[4];
        {
            f32x4 aG = *(const f32x4*)&bias_s[0][n0];
            aG = MFS(ld8(UhrA, UhrB, (wid * 2 + 0) * 64 + lane), hb0, aG);
            aG = MFS(ld8(UhrA, UhrB, (wid * 2 + 1) * 64 + lane), hb1, aG);
            h8 bx = *(const h8*)&xs[rrow * LDX + lg * 8];
            aG = MF16(WxrH[wid * 64 + lane], bx, aG);
            #pragma unroll
            for (int r = 0; r < 4; ++r)
                rg[r] = sig2(aG[r]);
        }
        // pass3: z gate + nX -> h-new (owner), commit new h to RB (buffer swap)
        // -- Uhz from LDS cache
        {
            f32x4 aG = *(const f32x4*)&bias_s[1][n0];
            aG = MFS(ld8(UhzA, UhzB, (wid * 2 + 0) * 64 + lane), hb0, aG);
            aG = MFS(ld8(UhzA, UhzB, (wid * 2 + 1) * 64 + lane), hb1, aG);
            h8 bx = *(const h8*)&xs[rrow * LDX + lg * 8];
            aG = MF16(WxzH[wid * 64 + lane], bx, aG);
            f32x4 aNx = *(const f32x4*)&bias_s[2][n0];
            aNx = MF16(WxnH[wid * 64 + lane], bx, aNx);
            float how[4];
            #pragma unroll
            for (int r = 0; r < 4; ++r)
                how[r] = __int_as_float(__builtin_amdgcn_ds_bpermute(sbase + 16 * r, __float_as_int(hs)));
            float hn[4];
            #pragma unroll
            for (int r = 0; r < 4; ++r) {
                float zg = sig2(aG[r]);
                float nv = tanh2(aNx[r] + rg[r] * aN[r]);
                hn[r] = (1.f - zg) * nv + zg * how[r];
            }
            float hng;
            GATHER(hng, hn);
            if (obs[rho] >= 0) hs = hng;
            RB[hoff] = fp8b(hs);
        }
        __syncthreads();   // a1s + RB(new h) + prefetch buffers visible
        // W2 GEMM + metrics: wave 0 only, overlaps other waves' next-event
        // phase-1 -- W2 from LDS cache (straggler path)
        if (wid == 0) {
            f32x4 aP = *(const f32x4*)&b2s[lg * 4];
            f32x4 aQ = zf;
            #pragma unroll
            for (int ks = 0; ks < 4; ++ks) {
                h8 ba = *(const h8*)&a1s[rrow * LDA1 + (2 * ks) * 32 + lg * 8];
                aP = MF16(W2L[(2 * ks) * 64 + lane], ba, aP);
                h8 bb = *(const h8*)&a1s[rrow * LDA1 + (2 * ks + 1) * 32 + lg * 8];
                aQ = MF16(W2L[(2 * ks + 1) * 64 + lane], bb, aQ);
            }
            if (obs[l16] >= 0) {
                float m0 = 0.f, m1 = 0.f, m2 = 0.f, m3 = 0.f;
                #pragma unroll
                for (int r = 0; r < 4; ++r) {
                    float p  = aP[r] + aQ[r];
                    float xt = ((const float*)&txv)[r];
                    float mt = ((const float*)&tmv)[r];
                    float diff = xt - p;
                    m0 += diff * diff * mt;
                    m1 += fabsf(diff) * mt;
                    m2 += fabsf(diff) * rcpf(xt + 1e-8f) * mt;
                    m3 += mt;
                }
                am0 += (double)m0;
                am1 += (double)m1;
                am2 += (double)m2;
                am3 += (double)m3;
            }
        }
    }

    __syncthreads();
    // deterministic metric reduction
    double v[4] = {am0, am1, am2, am3};
    #pragma unroll
    for (int m = 0; m < 4; ++m) {
        double t = v[m];
        for (int off = 32; off; off >>= 1) t += __shfl_down(t, off);
        if (lane == 0) wred[wid][m] = t;
    }
    __syncthreads();
    if (tid == 0) {
        for (int m = 0; m < 4; ++m) {
            double t = 0.0;
            for (int w = 0; w < 16; ++w) t += wred[w][m];
            partials[blockIdx.x * 4 + m] = t;
        }
    }
}

__global__ void finalize_k(const double* __restrict__ partials, float* __restrict__ out) {
    __shared__ double sd[4][4];
    int t = threadIdx.x;   // 256
    int l = t & 63, w = t >> 6;
    double v0 = partials[t * 4 + 0];
    double v1 = partials[t * 4 + 1];
    double v2 = partials[t * 4 + 2];
    double v3 = partials[t * 4 + 3];
    for (int off = 32; off; off >>= 1) {
        v0 += __shfl_down(v0, off);
        v1 += __shfl_down(v1, off);
        v2 += __shfl_down(v2, off);
        v3 += __shfl_down(v3, off);
    }
    if (l == 0) { sd[w][0] = v0; sd[w][1] = v1; sd[w][2] = v2; sd[w][3] = v3; }
    __syncthreads();
    if (t == 0) {
        double r0 = 0, r1 = 0, r2 = 0, r3 = 0;
        for (int i = 0; i < 4; ++i) { r0 += sd[i][0]; r1 += sd[i][1]; r2 += sd[i][2]; r3 += sd[i][3]; }
        out[0] = (float)(r0 / r3);
        out[1] = (float)(r1 / r3);
        out[2] = (float)(r2 / r3);
    }
}

extern "C" void kernel_launch(void* const* d_in, const int* in_sizes, int n_in,
                              void* d_out, int out_size, void* d_ws, size_t ws_size,
                              hipStream_t stream) {
    const float* X   = (const float*)d_in[0];
    const float* M   = (const float*)d_in[1];
    const int*  bidx = (const int*)d_in[2];
    const float* dtp = (const float*)d_in[3];
    const float* Wr  = (const float*)d_in[4];
    const float* brr = (const float*)d_in[5];
    const float* Wz  = (const float*)d_in[6];
    const float* bzz = (const float*)d_in[7];
    const float* Wh  = (const float*)d_in[8];
    const float* bhh = (const float*)d_in[9];
    const float* Wxr = (const float*)d_in[10];
    const float* Wxz = (const float*)d_in[11];
    const float* Wxn = (const float*)d_in[12];
    const float* Uhr = (const float*)d_in[13];
    const float* Uhz = (const float*)d_in[14];
    const float* Uhn = (const float*)d_in[15];
    const float* bxr = (const float*)d_in[16];
    const float* bxz = (const float*)d_in[17];
    const float* bxn = (const float*)d_in[18];
    const float* bhr = (const float*)d_in[19];
    const float* bhz = (const float*)d_in[20];
    const float* bhn = (const float*)d_in[21];
    const float* W1  = (const float*)d_in[22];
    const float* b1  = (const float*)d_in[23];
    const float* W2  = (const float*)d_in[24];
    const float* b2  = (const float*)d_in[25];

    char* w = (char*)d_ws;
    i32x8* WrQ  = (i32x8*)(w + 0 * 65536);
    i32x8* WzQ  = (i32x8*)(w + 1 * 65536);
    i32x8* WhQ  = (i32x8*)(w + 2 * 65536);
    i32x8* UhrQ = (i32x8*)(w + 3 * 65536);
    i32x8* UhzQ = (i32x8*)(w + 4 * 65536);
    i32x8* UhnQ = (i32x8*)(w + 5 * 65536);
    i32x8* W1Q  = (i32x8*)(w + 6 * 65536);
    _Float16* WxrH = (_Float16*)(w + 458752);
    _Float16* WxzH = (_Float16*)(w + 475136);
    _Float16* WxnH = (_Float16*)(w + 491520);
    _Float16* W2H  = (_Float16*)(w + 507904);
    int* inv = (int*)(w + 516096);
    _Float16* Xg = (_Float16*)(w + 778240);
    float* Tx = (float*)(w + 4972544);
    float* Tm = (float*)(w + 9166848);
    double* partials = (double*)(w + 13361152);

    prep_all<<<326, 256, 0, stream>>>(
        Wr, Wz, Wh, Uhr, Uhz, Uhn, W1, Wxr, Wxz, Wxn, W2,
        (int4*)WrQ, (int4*)WzQ, (int4*)WhQ, (int4*)UhrQ, (int4*)UhzQ,
        (int4*)UhnQ, (int4*)W1Q, WxrH, WxzH, WxnH, W2H, inv);
    gather_all<<<6272, 256, 0, stream>>>(X, M, bidx, inv, Xg, Tx, Tm);

    gruode_main<<<256, 1024, 0, stream>>>(Xg, Tx, Tm, dtp,
        brr, bzz, bhh, bxr, bxz, bxn, bhr, bhz, bhn, b1, b2,
        WrQ, WzQ, WhQ, UhrQ, UhzQ, UhnQ, W1Q,
        (const h8*)WxrH, (const h8*)WxzH, (const h8*)WxnH, (const h8*)W2H,
        inv, partials);

    finalize_k<<<1, 256, 0, stream>>>(partials, (float*)d_out);
}